// Round 3
// baseline (28.271 us; speedup 1.0000x reference)
//
#include <hip/hip_runtime.h>
#include <hip/hip_bf16.h>

typedef __attribute__((ext_vector_type(8))) short bf16x8;   // MFMA A/B frag (8 bf16)
typedef __attribute__((ext_vector_type(4))) float f32x4;    // MFMA C/D frag

constexpr int BM = 32;      // output rows (h) per block
constexpr int BN = 32;      // output cols (w) per block
constexpr int BK = 32;      // points per K-step
constexpr int NPTS = 4096;
constexpr int HH = 256;
constexpr int WW = 256;
constexpr int CAP = 512;    // max compacted points per tile (mean ~159, +28 sigma)

// S = sqrt(INV_VAR * log2(e)); exp(-INV_VAR*d^2) = exp2(-(S*d)^2)
#define SCALE_S 0.56621453f
// cutoff: dropped-point contribution <= 1e5*exp(-0.2222*100) = 2.2e-5 each
#define DCUT 10.0f

__device__ inline short f2bs(float x) {
    __hip_bfloat16 b = __float2bfloat16(x);   // RNE
    return __builtin_bit_cast(short, b);
}

__global__ __launch_bounds__(64, 2) void soft_raster_kernel(
    const float* __restrict__ p2d,   // (32, 4096, 2)
    const float* __restrict__ pz,    // (32, 4096)
    float* __restrict__ out)         // (32, 256, 256)
{
    const int bk   = blockIdx.z;
    const int tm   = blockIdx.y * BM;
    const int tn   = blockIdx.x * BN;
    const int lane = threadIdx.x;       // one wave per block

    __shared__ __align__(16) unsigned short lwy[BM * BK];  // [m][k], XOR-swizzled
    __shared__ __align__(16) unsigned short lwx[BN * BK];  // [n][k], XOR-swizzled
    __shared__ unsigned short lidx[CAP];                   // compacted point ids
    __shared__ float lys[BK];   // y * S
    __shared__ float lxs[BK];   // x * S
    __shared__ float lzi[BK];   // 1/max(z,1e-5), 0 for tail padding

    const int g = lane >> 4;    // k-group 0..3
    const int r = lane & 15;

    const size_t pbase = (size_t)bk * NPTS;
    const float2* __restrict__ pxy = reinterpret_cast<const float2*>(p2d) + pbase;

    // ---- single-pass in-wave ordered compaction of in-window points ----
    const float xlo = (float)tn - DCUT, xhi = (float)(tn + BN - 1) + DCUT;
    const float ylo = (float)tm - DCUT, yhi = (float)(tm + BM - 1) + DCUT;

    int base = 0;
    #pragma unroll 4
    for (int it = 0; it < NPTS / 64; ++it) {
        const int k = (it << 6) + lane;
        float2 xy = pxy[k];
        bool in = (xy.x > xlo) && (xy.x < xhi) && (xy.y > ylo) && (xy.y < yhi);
        unsigned long long b = __ballot(in);
        int pos = __popcll(b & ((1ull << lane) - 1ull));
        if (in && (base + pos) < CAP) lidx[base + pos] = (unsigned short)k;
        base += __popcll(b);     // wave-uniform
    }
    const int total = (base < CAP) ? base : CAP;

    f32x4 acc[2][2] = {};

    for (int k0 = 0; k0 < total; k0 += BK) {
        // ---- gather up to 32 compacted points (pre-scaled); tail = weight 0 ----
        if (lane < BK) {
            const int j = k0 + lane;
            float xs = 0.f, ys = 0.f, zi = 0.f;
            if (j < total) {
                const int kk = lidx[j];
                float2 xy = pxy[kk];
                float  z  = pz[pbase + kk];
                xs = xy.x * SCALE_S;
                ys = xy.y * SCALE_S;
                zi = __builtin_amdgcn_rcpf(fmaxf(z, 1e-5f));
            }
            lxs[lane] = xs; lys[lane] = ys; lzi[lane] = zi;
        }
        // single wave: compiler-ordered LDS (lgkmcnt), no barrier needed

        // ---- generate Wy (32x32) and Wx (32x32) bf16 tiles into LDS ----
        // chunk = 8 consecutive-k bf16 for one coordinate q -> one 16B write
        #pragma unroll
        for (int half = 0; half < 2; ++half) {
            const float* coord      = (half == 0) ? lys : lxs;
            unsigned short* dst     = (half == 0) ? lwy : lwx;
            const int       cb      = (half == 0) ? tm  : tn;
            #pragma unroll
            for (int it = 0; it < 2; ++it) {
                const int cc = lane + (it << 6);      // 0..127
                const int q  = cc >> 2;               // coordinate within tile
                const int kg = cc & 3;                // k-group (8 points)
                const float qs = (float)(cb + q) * SCALE_S;
                float4 c0 = *reinterpret_cast<const float4*>(&coord[kg * 8]);
                float4 c1 = *reinterpret_cast<const float4*>(&coord[kg * 8 + 4]);
                float e0 = exp2f(-((qs - c0.x) * (qs - c0.x)));
                float e1 = exp2f(-((qs - c0.y) * (qs - c0.y)));
                float e2 = exp2f(-((qs - c0.z) * (qs - c0.z)));
                float e3 = exp2f(-((qs - c0.w) * (qs - c0.w)));
                float e4 = exp2f(-((qs - c1.x) * (qs - c1.x)));
                float e5 = exp2f(-((qs - c1.y) * (qs - c1.y)));
                float e6 = exp2f(-((qs - c1.z) * (qs - c1.z)));
                float e7 = exp2f(-((qs - c1.w) * (qs - c1.w)));
                if (half == 0) {   // fold inv_z into Wy
                    float4 z0 = *reinterpret_cast<const float4*>(&lzi[kg * 8]);
                    float4 z1 = *reinterpret_cast<const float4*>(&lzi[kg * 8 + 4]);
                    e0 *= z0.x; e1 *= z0.y; e2 *= z0.z; e3 *= z0.w;
                    e4 *= z1.x; e5 *= z1.y; e6 *= z1.z; e7 *= z1.w;
                }
                bf16x8 v;
                v[0] = f2bs(e0); v[1] = f2bs(e1); v[2] = f2bs(e2); v[3] = f2bs(e3);
                v[4] = f2bs(e4); v[5] = f2bs(e5); v[6] = f2bs(e6); v[7] = f2bs(e7);
                const int idx = ((q << 5) + (kg << 3)) ^ ((q & 3) << 3);  // swizzle
                *reinterpret_cast<bf16x8*>(&dst[idx]) = v;
            }
        }

        // ---- MFMA: one K-substep of 32, 2x2 fragments of 16x16 ----
        {
            bf16x8 af[2], bfr[2];
            #pragma unroll
            for (int i = 0; i < 2; ++i) {
                const int qa = (i << 4) + r;
                af[i] = *reinterpret_cast<const bf16x8*>(
                    &lwy[((qa << 5) + (g << 3)) ^ ((qa & 3) << 3)]);
                bfr[i] = *reinterpret_cast<const bf16x8*>(
                    &lwx[((qa << 5) + (g << 3)) ^ ((qa & 3) << 3)]);
            }
            #pragma unroll
            for (int mi = 0; mi < 2; ++mi)
                #pragma unroll
                for (int ni = 0; ni < 2; ++ni)
                    acc[mi][ni] = __builtin_amdgcn_mfma_f32_16x16x32_bf16(
                        af[mi], bfr[ni], acc[mi][ni], 0, 0, 0);
        }
    }

    // ---- epilogue: C/D layout col=lane&15, row=4*(lane>>4)+reg ----
    float* obase = out + (size_t)bk * (HH * WW);
    #pragma unroll
    for (int mi = 0; mi < 2; ++mi) {
        #pragma unroll
        for (int ni = 0; ni < 2; ++ni) {
            const int col  = tn + (ni << 4) + r;
            const int row0 = tm + (mi << 4) + (g << 2);
            #pragma unroll
            for (int j = 0; j < 4; ++j)
                obase[(size_t)(row0 + j) * WW + col] = acc[mi][ni][j];
        }
    }
}

extern "C" void kernel_launch(void* const* d_in, const int* in_sizes, int n_in,
                              void* d_out, int out_size, void* d_ws, size_t ws_size,
                              hipStream_t stream) {
    const float* p2d = (const float*)d_in[0];
    const float* pz  = (const float*)d_in[1];
    float* out       = (float*)d_out;
    const int nbk    = in_sizes[1] / NPTS;   // B*K = 32
    dim3 grid(WW / BN, HH / BM, nbk);        // (8, 8, 32) = 2048 WGs
    dim3 block(64);
    hipLaunchKernelGGL(soft_raster_kernel, grid, block, 0, stream, p2d, pz, out);
}